// Round 9
// baseline (193.749 us; speedup 1.0000x reference)
//
#include <hip/hip_runtime.h>

#define N_CELL 8192
#define N_DRUG 4096

typedef float f32x4 __attribute__((ext_vector_type(4)));

// Output layout (floats):
//   0                       : agg_cell_lp [N_CELL][N_DRUG]
//   OFF1 = N_CELL*N_DRUG    : agg_drug_lp [N_DRUG][N_CELL]
//   OFF2 = 2*N_CELL*N_DRUG  : self_cell_lp [N_CELL][N_CELL]
//   OFF3 = OFF2 + N_CELL^2  : self_drug_lp [N_DRUG][N_DRUG]
static constexpr size_t OFF1 = (size_t)N_CELL * N_DRUG;
static constexpr size_t OFF2 = 2ull * N_CELL * N_DRUG;
static constexpr size_t OFF3 = OFF2 + (size_t)N_CELL * N_CELL;
static constexpr size_t FILL_F4 = ((size_t)N_CELL * N_CELL + (size_t)N_DRUG * N_DRUG) / 4; // 20,971,520

// ---- D1 (R7 structure): 512 sums + 1280 fill blocks, 262KB/256KB each ----
#define SUM_BLOCKS 512
#define FILL_BLOCKS 1280
#define MEGA_BLOCKS (SUM_BLOCKS + FILL_BLOCKS)
static constexpr size_t FILL_PER_BLOCK = FILL_F4 / FILL_BLOCKS;  // 16384 f4 = 256KB, exact

__global__ __launch_bounds__(256, 8) void mega_kernel(const float* __restrict__ adj,
                                                      float* __restrict__ rowsum,
                                                      float* __restrict__ colsum,
                                                      float* __restrict__ fill_base) {
    int b = blockIdx.x;
    int tid = threadIdx.x;
    if (b >= SUM_BLOCKS) {
        // plain-store zero-fill: 16384 f4 contiguous per block (256 KB)
        f32x4 z = {0.f, 0.f, 0.f, 0.f};
        f32x4* p = reinterpret_cast<f32x4*>(fill_base) + (size_t)(b - SUM_BLOCKS) * FILL_PER_BLOCK;
#pragma unroll 4
        for (size_t i = tid; i < FILL_PER_BLOCK; i += 256) {
            p[i] = z;
        }
        return;
    }
    __shared__ float part[64][65];
    int cb = b & 3, rb = b >> 2;
    int c0 = cb * 1024, r0 = rb * 64;
    const f32x4* ap = reinterpret_cast<const f32x4*>(adj + (size_t)r0 * N_DRUG + c0) + tid;
    f32x4 cacc = {0.f, 0.f, 0.f, 0.f};
#pragma unroll 4
    for (int r = 0; r < 64; ++r) {
        f32x4 v = ap[(size_t)r * (N_DRUG / 4)];
        cacc += v;
        float h = (v.x + v.y) + (v.z + v.w);
        h += __shfl_down(h, 1, 64);
        h += __shfl_down(h, 2, 64);     // lanes ≡0 mod 4 hold 16-col partials
        if ((tid & 3) == 0) part[r][tid >> 2] = h;
    }
    __syncthreads();
    if (tid < 64) {
        float s = 0.f;
#pragma unroll 8
        for (int j = 0; j < 64; ++j) s += part[tid][j];
        atomicAdd(&rowsum[r0 + tid], s);  // 4 partials per row
    }
    int c = c0 + tid * 4;
    atomicAdd(&colsum[c + 0], cacc.x);    // 128 partials per col
    atomicAdd(&colsum[c + 1], cacc.y);
    atomicAdd(&colsum[c + 2], cacc.z);
    atomicAdd(&colsum[c + 3], cacc.w);
}

// ---- D2 (R7 structure): 128x128 region as 4x 64x64 LDS subtiles, 17.7KB LDS,
// 8 blocks/CU; plain stores (A/B vs R7's non-temporal). ----
#define SCALE_TILES 2048   // 32 col-tiles x 64 row-tiles
#define DIAG_BLOCKS 48     // 48*256 = 12288 = N_CELL + N_DRUG
__global__ __launch_bounds__(256, 8) void scale_kernel(const float* __restrict__ adj,
                                                       const float* __restrict__ rowsum,
                                                       const float* __restrict__ colsum,
                                                       float* __restrict__ out) {
    int tid = threadIdx.x;
    int b = blockIdx.x;
    if (b >= SCALE_TILES) {  // diag role (fill completed in D1)
        int idx = (b - SCALE_TILES) * 256 + tid;
        if (idx < N_CELL) {
            out[OFF2 + (size_t)idx * (N_CELL + 1)] = 1.0f / (rowsum[idx] + 1.0f) + 1.0f;
        } else {
            int k = idx - N_CELL;   // < N_DRUG by construction
            out[OFF3 + (size_t)k * (N_DRUG + 1)] = 1.0f / (colsum[k] + 1.0f) + 1.0f;
        }
        return;
    }
    __shared__ float lds[64][69];
    int tx = tid & 15;   // 16 x f32x4 = 64 cols
    int ty = tid >> 4;   // 16 rows per pass
    int c0 = (b & 31) * 128;   // 32 col-tiles
    int r0 = (b >> 5) * 128;   // 64 row-tiles
    float* aggd = out + OFF1;
#pragma unroll 1
    for (int s = 0; s < 4; ++s) {
        int cc = c0 + (s & 1) * 64;
        int rr0 = r0 + (s >> 1) * 64;
        f32x4 cs = *reinterpret_cast<const f32x4*>(colsum + cc + tx * 4);
        f32x4 dy;
        dy.x = rsqrtf(cs.x + 1.0f);
        dy.y = rsqrtf(cs.y + 1.0f);
        dy.z = rsqrtf(cs.z + 1.0f);
        dy.w = rsqrtf(cs.w + 1.0f);
#pragma unroll
        for (int q = 0; q < 4; ++q) {
            int rr = q * 16 + ty;
            int r = rr0 + rr;
            float dx = rsqrtf(rowsum[r] + 1.0f);
            f32x4 v = *reinterpret_cast<const f32x4*>(adj + (size_t)r * N_DRUG + cc + tx * 4);
            f32x4 o = v * dx;
            o *= dy;
            *reinterpret_cast<f32x4*>(out + (size_t)r * N_DRUG + cc + tx * 4) = o;
            lds[rr][tx * 4 + 0] = o.x;
            lds[rr][tx * 4 + 1] = o.y;
            lds[rr][tx * 4 + 2] = o.z;
            lds[rr][tx * 4 + 3] = o.w;
        }
        __syncthreads();
#pragma unroll
        for (int q = 0; q < 4; ++q) {
            int dr = q * 16 + ty;
            f32x4 o;
            o.x = lds[tx * 4 + 0][dr];
            o.y = lds[tx * 4 + 1][dr];
            o.z = lds[tx * 4 + 2][dr];
            o.w = lds[tx * 4 + 3][dr];
            *reinterpret_cast<f32x4*>(aggd + (size_t)(cc + dr) * N_CELL + rr0 + tx * 4) = o;
        }
        __syncthreads();   // before next sub-tile reuses lds
    }
}

extern "C" void kernel_launch(void* const* d_in, const int* in_sizes, int n_in,
                              void* d_out, int out_size, void* d_ws, size_t ws_size,
                              hipStream_t stream) {
    const float* adj = (const float*)d_in[0];
    float* out = (float*)d_out;
    float* rowsum = (float*)d_ws;        // N_CELL floats
    float* colsum = rowsum + N_CELL;     // N_DRUG floats

    // zero the atomic accumulators (contiguous 48 KB)
    (void)hipMemsetAsync(d_ws, 0, (N_CELL + N_DRUG) * sizeof(float), stream);

    mega_kernel<<<MEGA_BLOCKS, 256, 0, stream>>>(adj, rowsum, colsum, out + OFF2);
    scale_kernel<<<SCALE_TILES + DIAG_BLOCKS, 256, 0, stream>>>(adj, rowsum, colsum, out);
}

// Round 10
// 177.923 us; speedup vs baseline: 1.0889x; 1.0889x over previous
//
#include <hip/hip_runtime.h>
#include <stdint.h>

#define N_CELL 8192
#define N_DRUG 4096

typedef float f32x4 __attribute__((ext_vector_type(4)));

// Output layout (floats):
//   0                       : agg_cell_lp [N_CELL][N_DRUG]
//   OFF1 = N_CELL*N_DRUG    : agg_drug_lp [N_DRUG][N_CELL]
//   OFF2 = 2*N_CELL*N_DRUG  : self_cell_lp [N_CELL][N_CELL]
//   OFF3 = OFF2 + N_CELL^2  : self_drug_lp [N_DRUG][N_DRUG]
static constexpr size_t OFF1 = (size_t)N_CELL * N_DRUG;
static constexpr size_t OFF2 = 2ull * N_CELL * N_DRUG;
static constexpr size_t CELLSZ = (size_t)N_CELL * N_CELL;                    // 67,108,864 floats
static constexpr size_t FILL_F4 = (CELLSZ + (size_t)N_DRUG * N_DRUG) / 4;   // 20,971,520 f4

// ---- D1: pure-read fused row+col sums. 1024 blocks, tile = 32 rows x 1024 cols. ----
#define SUM_BLOCKS 1024
__global__ __launch_bounds__(256, 8) void sums_kernel(const float* __restrict__ adj,
                                                      float* __restrict__ rowsum,
                                                      float* __restrict__ colsum) {
    __shared__ float part[32][65];
    int tid = threadIdx.x;
    int cb = blockIdx.x & 3;    // 4 col blocks  -> 1024 cols
    int rb = blockIdx.x >> 2;   // 256 row blocks -> 32 rows
    int c0 = cb * 1024;
    int r0 = rb * 32;
    const f32x4* ap = reinterpret_cast<const f32x4*>(adj + (size_t)r0 * N_DRUG + c0) + tid;
    f32x4 cacc = {0.f, 0.f, 0.f, 0.f};
#pragma unroll 4
    for (int r = 0; r < 32; ++r) {
        f32x4 v = ap[(size_t)r * (N_DRUG / 4)];
        cacc += v;
        float h = (v.x + v.y) + (v.z + v.w);
        h += __shfl_down(h, 1, 64);
        h += __shfl_down(h, 2, 64);     // lanes ≡0 mod 4 hold 16-col partials
        if ((tid & 3) == 0) part[r][tid >> 2] = h;
    }
    __syncthreads();
    if (tid < 32) {
        float s = 0.f;
#pragma unroll 8
        for (int j = 0; j < 64; ++j) s += part[tid][j];   // banks (tid+j)%32: conflict-free
        atomicAdd(&rowsum[r0 + tid], s);  // 4 partials per row
    }
    int c = c0 + tid * 4;
    atomicAdd(&colsum[c + 0], cacc.x);    // 256 partials per col
    atomicAdd(&colsum[c + 1], cacc.y);
    atomicAdd(&colsum[c + 2], cacc.z);
    atomicAdd(&colsum[c + 3], cacc.w);
}

// ---- D2: 2048 blocks, each: (a) 128x128 scale+transpose tile (R7-proven
// structure, 17.7KB LDS, 8 blocks/CU), then (b) nt-fill its own 10240-f4 chunk
// of the self matrices with diag values folded into the same stores. ----
#define SCALE_TILES 2048   // 32 col-tiles x 64 row-tiles
static constexpr uint32_t FILL_PER_BLOCK = (uint32_t)(FILL_F4 / SCALE_TILES);  // 10240 f4

__global__ __launch_bounds__(256, 8) void scale_fill_kernel(const float* __restrict__ adj,
                                                            const float* __restrict__ rowsum,
                                                            const float* __restrict__ colsum,
                                                            float* __restrict__ out) {
    int tid = threadIdx.x;
    int b = blockIdx.x;
    __shared__ float lds[64][69];
    int tx = tid & 15;   // 16 x f32x4 = 64 cols
    int ty = tid >> 4;   // 16 rows per pass
    int c0 = (b & 31) * 128;   // 32 col-tiles
    int r0 = (b >> 5) * 128;   // 64 row-tiles
    float* aggd = out + OFF1;
#pragma unroll 1
    for (int s = 0; s < 4; ++s) {
        int cc = c0 + (s & 1) * 64;
        int rr0 = r0 + (s >> 1) * 64;
        f32x4 cs = *reinterpret_cast<const f32x4*>(colsum + cc + tx * 4);
        f32x4 dy;
        dy.x = rsqrtf(cs.x + 1.0f);
        dy.y = rsqrtf(cs.y + 1.0f);
        dy.z = rsqrtf(cs.z + 1.0f);
        dy.w = rsqrtf(cs.w + 1.0f);
#pragma unroll
        for (int q = 0; q < 4; ++q) {
            int rr = q * 16 + ty;
            int r = rr0 + rr;
            float dx = rsqrtf(rowsum[r] + 1.0f);
            f32x4 v = *reinterpret_cast<const f32x4*>(adj + (size_t)r * N_DRUG + cc + tx * 4);
            f32x4 o = v * dx;
            o *= dy;
            __builtin_nontemporal_store(
                o, reinterpret_cast<f32x4*>(out + (size_t)r * N_DRUG + cc + tx * 4));
            lds[rr][tx * 4 + 0] = o.x;
            lds[rr][tx * 4 + 1] = o.y;
            lds[rr][tx * 4 + 2] = o.z;
            lds[rr][tx * 4 + 3] = o.w;
        }
        __syncthreads();
#pragma unroll
        for (int q = 0; q < 4; ++q) {
            int dr = q * 16 + ty;
            f32x4 o;
            o.x = lds[tx * 4 + 0][dr];
            o.y = lds[tx * 4 + 1][dr];
            o.z = lds[tx * 4 + 2][dr];
            o.w = lds[tx * 4 + 3][dr];
            __builtin_nontemporal_store(
                o, reinterpret_cast<f32x4*>(aggd + (size_t)(cc + dr) * N_CELL + rr0 + tx * 4));
        }
        __syncthreads();   // before next sub-tile reuses lds
    }

    // ---- fill role: my contiguous 10240-f4 chunk, diag folded into the stores.
    // self_cell diag k at float offset k*8193 (k<8192); self_drug diag k at
    // CELLSZ + k*4097 (k<4096). A f4 never straddles the region boundary
    // (CELLSZ % 4 == 0), and at most one of its 4 floats is a diag element.
    f32x4* fp = reinterpret_cast<f32x4*>(out + OFF2);
    const uint32_t CELL_F = (uint32_t)CELLSZ;
    uint32_t base = (uint32_t)b * FILL_PER_BLOCK;
#pragma unroll 4
    for (uint32_t i = tid; i < FILL_PER_BLOCK; i += 256) {
        uint32_t g = base + i;
        uint32_t o = g * 4u;            // float offset within fill region
        f32x4 v = {0.f, 0.f, 0.f, 0.f};
        if (o < CELL_F) {
            uint32_t q = o / 8193u;
            uint32_t m = o - q * 8193u;
            if (m == 0u)         v.x = 1.0f / (rowsum[q] + 1.0f) + 1.0f;
            else if (m == 8192u) v.y = 1.0f / (rowsum[q + 1] + 1.0f) + 1.0f;
            else if (m == 8191u) v.z = 1.0f / (rowsum[q + 1] + 1.0f) + 1.0f;
            else if (m == 8190u) v.w = 1.0f / (rowsum[q + 1] + 1.0f) + 1.0f;
        } else {
            uint32_t od = o - CELL_F;
            uint32_t q = od / 4097u;
            uint32_t m = od - q * 4097u;
            if (m == 0u)         v.x = 1.0f / (colsum[q] + 1.0f) + 1.0f;
            else if (m == 4096u) v.y = 1.0f / (colsum[q + 1] + 1.0f) + 1.0f;
            else if (m == 4095u) v.z = 1.0f / (colsum[q + 1] + 1.0f) + 1.0f;
            else if (m == 4094u) v.w = 1.0f / (colsum[q + 1] + 1.0f) + 1.0f;
        }
        __builtin_nontemporal_store(v, fp + g);
    }
}

extern "C" void kernel_launch(void* const* d_in, const int* in_sizes, int n_in,
                              void* d_out, int out_size, void* d_ws, size_t ws_size,
                              hipStream_t stream) {
    const float* adj = (const float*)d_in[0];
    float* out = (float*)d_out;
    float* rowsum = (float*)d_ws;        // N_CELL floats
    float* colsum = rowsum + N_CELL;     // N_DRUG floats

    // zero the atomic accumulators (contiguous 48 KB)
    (void)hipMemsetAsync(d_ws, 0, (N_CELL + N_DRUG) * sizeof(float), stream);

    sums_kernel<<<SUM_BLOCKS, 256, 0, stream>>>(adj, rowsum, colsum);
    scale_fill_kernel<<<SCALE_TILES, 256, 0, stream>>>(adj, rowsum, colsum, out);
}

// Round 11
// 159.733 us; speedup vs baseline: 1.2130x; 1.1139x over previous
//
#include <hip/hip_runtime.h>

#define N_CELL 8192
#define N_DRUG 4096

typedef float f32x4 __attribute__((ext_vector_type(4)));

// Output layout (floats):
//   0                       : agg_cell_lp [N_CELL][N_DRUG]
//   OFF1 = N_CELL*N_DRUG    : agg_drug_lp [N_DRUG][N_CELL]
//   OFF2 = 2*N_CELL*N_DRUG  : self_cell_lp [N_CELL][N_CELL]
//   OFF3 = OFF2 + N_CELL^2  : self_drug_lp [N_DRUG][N_DRUG]
static constexpr size_t OFF1 = (size_t)N_CELL * N_DRUG;
static constexpr size_t OFF2 = 2ull * N_CELL * N_DRUG;
static constexpr size_t OFF3 = OFF2 + (size_t)N_CELL * N_CELL;
static constexpr size_t FILL_F4 = ((size_t)N_CELL * N_CELL + (size_t)N_DRUG * N_DRUG) / 4; // 20,971,520

// ---- D1 (R7-proven, verbatim): 512 sums + 1280 nt-fill blocks, ~260KB each ----
#define SUM_BLOCKS 512
#define FILL_BLOCKS 1280
#define MEGA_BLOCKS (SUM_BLOCKS + FILL_BLOCKS)
static constexpr size_t FILL_PER_BLOCK = FILL_F4 / FILL_BLOCKS;  // 16384 f4 = 256KB, exact

__global__ __launch_bounds__(256, 8) void mega_kernel(const float* __restrict__ adj,
                                                      float* __restrict__ rowsum,
                                                      float* __restrict__ colsum,
                                                      float* __restrict__ fill_base) {
    int b = blockIdx.x;
    int tid = threadIdx.x;
    if (b >= SUM_BLOCKS) {
        f32x4 z = {0.f, 0.f, 0.f, 0.f};
        f32x4* p = reinterpret_cast<f32x4*>(fill_base) + (size_t)(b - SUM_BLOCKS) * FILL_PER_BLOCK;
#pragma unroll 4
        for (size_t i = tid; i < FILL_PER_BLOCK; i += 256) {
            __builtin_nontemporal_store(z, p + i);
        }
        return;
    }
    __shared__ float part[64][65];
    int cb = b & 3, rb = b >> 2;
    int c0 = cb * 1024, r0 = rb * 64;
    const f32x4* ap = reinterpret_cast<const f32x4*>(adj + (size_t)r0 * N_DRUG + c0) + tid;
    f32x4 cacc = {0.f, 0.f, 0.f, 0.f};
#pragma unroll 4
    for (int r = 0; r < 64; ++r) {
        f32x4 v = ap[(size_t)r * (N_DRUG / 4)];
        cacc += v;
        float h = (v.x + v.y) + (v.z + v.w);
        h += __shfl_down(h, 1, 64);
        h += __shfl_down(h, 2, 64);     // lanes ≡0 mod 4 hold 16-col partials
        if ((tid & 3) == 0) part[r][tid >> 2] = h;
    }
    __syncthreads();
    if (tid < 64) {
        float s = 0.f;
#pragma unroll 8
        for (int j = 0; j < 64; ++j) s += part[tid][j];
        atomicAdd(&rowsum[r0 + tid], s);  // 4 partials per row
    }
    int c = c0 + tid * 4;
    atomicAdd(&colsum[c + 0], cacc.x);    // 128 partials per col
    atomicAdd(&colsum[c + 1], cacc.y);
    atomicAdd(&colsum[c + 2], cacc.z);
    atomicAdd(&colsum[c + 3], cacc.w);
}

// ---- D2: 512-thread blocks, 128-row x 64-col LDS stage (33 KB -> 4 blocks/CU
// = 32 waves/CU, same occupancy as R7), transposed agg_drug writes are
// 128 cells = 512 B per instruction (vs R7's 256 B). Each block does 4
// adjacent col sub-tiles (128 rows x 256 cols total). 24 diag blocks first. ----
#define DIAG_BLOCKS 24     // 24*512 = 12288 = N_CELL + N_DRUG
#define SCALE_BLOCKS 1024  // 64 row-tiles x 16 col-groups
__global__ __launch_bounds__(512, 8) void scale_kernel(const float* __restrict__ adj,
                                                       const float* __restrict__ rowsum,
                                                       const float* __restrict__ colsum,
                                                       float* __restrict__ out) {
    int tid = threadIdx.x;
    int b = blockIdx.x;
    if (b < DIAG_BLOCKS) {   // diag role (fill completes in D1)
        int idx = b * 512 + tid;
        if (idx < N_CELL) {
            out[OFF2 + (size_t)idx * (N_CELL + 1)] = 1.0f / (rowsum[idx] + 1.0f) + 1.0f;
        } else {
            int k = idx - N_CELL;   // < N_DRUG by construction
            out[OFF3 + (size_t)k * (N_DRUG + 1)] = 1.0f / (colsum[k] + 1.0f) + 1.0f;
        }
        return;
    }
    __shared__ float lds[128][65];   // 33.3 KB
    int t = b - DIAG_BLOCKS;
    int rt = t >> 4;           // 64 row-tiles (128 rows each)
    int ci = t & 15;           // 16 col-groups (256 cols each)
    int r0 = rt * 128;
    int cg = ci * 256;
    float* aggd = out + OFF1;

    // phase-1 thread map: tx f4-col (16 x 16B = 64 cols), ty row 0..31
    int tx = tid & 15;
    int ty = tid >> 4;
    // phase-2 thread map: tx2 cell-f4 (32 x 16B = 512 B), dj drug-row 0..15
    int tx2 = tid & 31;
    int dj = tid >> 5;

    // rowsum scales: fixed across sub-tiles (rr = i*32+ty independent of s)
    float dx0 = rsqrtf(rowsum[r0 + 0 * 32 + ty] + 1.0f);
    float dx1 = rsqrtf(rowsum[r0 + 1 * 32 + ty] + 1.0f);
    float dx2 = rsqrtf(rowsum[r0 + 2 * 32 + ty] + 1.0f);
    float dx3 = rsqrtf(rowsum[r0 + 3 * 32 + ty] + 1.0f);

#pragma unroll 1
    for (int s = 0; s < 4; ++s) {
        int cc = cg + s * 64;
        f32x4 cs = *reinterpret_cast<const f32x4*>(colsum + cc + tx * 4);
        f32x4 dy;
        dy.x = rsqrtf(cs.x + 1.0f);
        dy.y = rsqrtf(cs.y + 1.0f);
        dy.z = rsqrtf(cs.z + 1.0f);
        dy.w = rsqrtf(cs.w + 1.0f);
#pragma unroll
        for (int i = 0; i < 4; ++i) {
            int rr = i * 32 + ty;
            int r = r0 + rr;
            float dx = (i == 0) ? dx0 : (i == 1) ? dx1 : (i == 2) ? dx2 : dx3;
            f32x4 v = *reinterpret_cast<const f32x4*>(adj + (size_t)r * N_DRUG + cc + tx * 4);
            f32x4 o = v * dx;
            o *= dy;
            __builtin_nontemporal_store(
                o, reinterpret_cast<f32x4*>(out + (size_t)r * N_DRUG + cc + tx * 4));
            lds[rr][tx * 4 + 0] = o.x;
            lds[rr][tx * 4 + 1] = o.y;
            lds[rr][tx * 4 + 2] = o.z;
            lds[rr][tx * 4 + 3] = o.w;
        }
        __syncthreads();
#pragma unroll
        for (int i = 0; i < 4; ++i) {
            int dd = i * 16 + dj;       // drug col within sub-tile
            f32x4 o;
            o.x = lds[tx2 * 4 + 0][dd];
            o.y = lds[tx2 * 4 + 1][dd];
            o.z = lds[tx2 * 4 + 2][dd];
            o.w = lds[tx2 * 4 + 3][dd];
            __builtin_nontemporal_store(
                o, reinterpret_cast<f32x4*>(aggd + (size_t)(cc + dd) * N_CELL + r0 + tx2 * 4));
        }
        __syncthreads();   // before next sub-tile reuses lds
    }
}

extern "C" void kernel_launch(void* const* d_in, const int* in_sizes, int n_in,
                              void* d_out, int out_size, void* d_ws, size_t ws_size,
                              hipStream_t stream) {
    const float* adj = (const float*)d_in[0];
    float* out = (float*)d_out;
    float* rowsum = (float*)d_ws;        // N_CELL floats
    float* colsum = rowsum + N_CELL;     // N_DRUG floats

    // zero the atomic accumulators (contiguous 48 KB)
    (void)hipMemsetAsync(d_ws, 0, (N_CELL + N_DRUG) * sizeof(float), stream);

    mega_kernel<<<MEGA_BLOCKS, 256, 0, stream>>>(adj, rowsum, colsum, out + OFF2);
    scale_kernel<<<DIAG_BLOCKS + SCALE_BLOCKS, 512, 0, stream>>>(adj, rowsum, colsum, out);
}

// Round 12
// 152.297 us; speedup vs baseline: 1.2722x; 1.0488x over previous
//
#include <hip/hip_runtime.h>

#define N_CELL 8192
#define N_DRUG 4096

typedef float f32x4 __attribute__((ext_vector_type(4)));

// Output layout (floats):
//   0                       : agg_cell_lp [N_CELL][N_DRUG]
//   OFF1 = N_CELL*N_DRUG    : agg_drug_lp [N_DRUG][N_CELL]
//   OFF2 = 2*N_CELL*N_DRUG  : self_cell_lp [N_CELL][N_CELL]
//   OFF3 = OFF2 + N_CELL^2  : self_drug_lp [N_DRUG][N_DRUG]
static constexpr size_t OFF1 = (size_t)N_CELL * N_DRUG;
static constexpr size_t OFF2 = 2ull * N_CELL * N_DRUG;
static constexpr size_t OFF3 = OFF2 + (size_t)N_CELL * N_CELL;
static constexpr size_t FILL_F4 = ((size_t)N_CELL * N_CELL + (size_t)N_DRUG * N_DRUG) / 4; // 20,971,520

// ---- D1: 512 sums blocks + 1280 fill blocks, per-block work balanced at ~260 KB.
// nt stores mandatory (R9: plain stores cost +40 us via L2/MALL write-allocate). ----
#define SUM_BLOCKS 512
#define FILL_BLOCKS 1280
#define MEGA_BLOCKS (SUM_BLOCKS + FILL_BLOCKS)
static constexpr size_t FILL_PER_BLOCK = FILL_F4 / FILL_BLOCKS;  // 16384 f4 = 256KB, exact

__global__ __launch_bounds__(256, 8) void mega_kernel(const float* __restrict__ adj,
                                                      float* __restrict__ rowsum,
                                                      float* __restrict__ colsum,
                                                      float* __restrict__ fill_base) {
    int b = blockIdx.x;
    int tid = threadIdx.x;
    if (b >= SUM_BLOCKS) {
        // nt zero-fill: 16384 f4 contiguous per block (256 KB)
        f32x4 z = {0.f, 0.f, 0.f, 0.f};
        f32x4* p = reinterpret_cast<f32x4*>(fill_base) + (size_t)(b - SUM_BLOCKS) * FILL_PER_BLOCK;
#pragma unroll 4
        for (size_t i = tid; i < FILL_PER_BLOCK; i += 256) {
            __builtin_nontemporal_store(z, p + i);
        }
        return;
    }
    // sums role: 64 rows x 1024 cols
    __shared__ float part[64][65];
    int cb = b & 3, rb = b >> 2;
    int c0 = cb * 1024, r0 = rb * 64;
    const f32x4* ap = reinterpret_cast<const f32x4*>(adj + (size_t)r0 * N_DRUG + c0) + tid;
    f32x4 cacc = {0.f, 0.f, 0.f, 0.f};
#pragma unroll 4
    for (int r = 0; r < 64; ++r) {
        f32x4 v = ap[(size_t)r * (N_DRUG / 4)];
        cacc += v;
        float h = (v.x + v.y) + (v.z + v.w);
        h += __shfl_down(h, 1, 64);
        h += __shfl_down(h, 2, 64);     // lanes ≡0 mod 4 hold 16-col partials
        if ((tid & 3) == 0) part[r][tid >> 2] = h;
    }
    __syncthreads();
    if (tid < 64) {
        float s = 0.f;
#pragma unroll 8
        for (int j = 0; j < 64; ++j) s += part[tid][j];
        atomicAdd(&rowsum[r0 + tid], s);  // 4 partials per row
    }
    int c = c0 + tid * 4;
    atomicAdd(&colsum[c + 0], cacc.x);    // 128 partials per col
    atomicAdd(&colsum[c + 1], cacc.y);
    atomicAdd(&colsum[c + 2], cacc.z);
    atomicAdd(&colsum[c + 3], cacc.w);
}

// ---- D2: scale+transpose on 128x128 regions as 4x 64x64 LDS subtiles
// (17.7 KB LDS, occupancy pinned at 8 blocks/CU = 32 waves/CU), nt stores. ----
#define SCALE_TILES 2048   // 32 col-tiles x 64 row-tiles
#define DIAG_BLOCKS 48     // 48*256 = 12288 = N_CELL + N_DRUG
__global__ __launch_bounds__(256, 8) void scale_kernel(const float* __restrict__ adj,
                                                       const float* __restrict__ rowsum,
                                                       const float* __restrict__ colsum,
                                                       float* __restrict__ out) {
    int tid = threadIdx.x;
    int b = blockIdx.x;
    if (b >= SCALE_TILES) {  // diag role (fill completed in D1)
        int idx = (b - SCALE_TILES) * 256 + tid;
        if (idx < N_CELL) {
            out[OFF2 + (size_t)idx * (N_CELL + 1)] = 1.0f / (rowsum[idx] + 1.0f) + 1.0f;
        } else {
            int k = idx - N_CELL;   // < N_DRUG by construction
            out[OFF3 + (size_t)k * (N_DRUG + 1)] = 1.0f / (colsum[k] + 1.0f) + 1.0f;
        }
        return;
    }
    __shared__ float lds[64][69];
    int tx = tid & 15;   // 16 x f32x4 = 64 cols
    int ty = tid >> 4;   // 16 rows per pass
    int c0 = (b & 31) * 128;   // 32 col-tiles
    int r0 = (b >> 5) * 128;   // 64 row-tiles
    float* aggd = out + OFF1;
#pragma unroll 1
    for (int s = 0; s < 4; ++s) {
        int cc = c0 + (s & 1) * 64;
        int rr0 = r0 + (s >> 1) * 64;
        f32x4 cs = *reinterpret_cast<const f32x4*>(colsum + cc + tx * 4);
        f32x4 dy;
        dy.x = rsqrtf(cs.x + 1.0f);
        dy.y = rsqrtf(cs.y + 1.0f);
        dy.z = rsqrtf(cs.z + 1.0f);
        dy.w = rsqrtf(cs.w + 1.0f);
#pragma unroll
        for (int q = 0; q < 4; ++q) {
            int rr = q * 16 + ty;
            int r = rr0 + rr;
            float dx = rsqrtf(rowsum[r] + 1.0f);
            f32x4 v = *reinterpret_cast<const f32x4*>(adj + (size_t)r * N_DRUG + cc + tx * 4);
            f32x4 o = v * dx;
            o *= dy;
            __builtin_nontemporal_store(
                o, reinterpret_cast<f32x4*>(out + (size_t)r * N_DRUG + cc + tx * 4));
            lds[rr][tx * 4 + 0] = o.x;
            lds[rr][tx * 4 + 1] = o.y;
            lds[rr][tx * 4 + 2] = o.z;
            lds[rr][tx * 4 + 3] = o.w;
        }
        __syncthreads();
#pragma unroll
        for (int q = 0; q < 4; ++q) {
            int dr = q * 16 + ty;
            f32x4 o;
            o.x = lds[tx * 4 + 0][dr];
            o.y = lds[tx * 4 + 1][dr];
            o.z = lds[tx * 4 + 2][dr];
            o.w = lds[tx * 4 + 3][dr];
            __builtin_nontemporal_store(
                o, reinterpret_cast<f32x4*>(aggd + (size_t)(cc + dr) * N_CELL + rr0 + tx * 4));
        }
        __syncthreads();   // before next sub-tile reuses lds
    }
}

extern "C" void kernel_launch(void* const* d_in, const int* in_sizes, int n_in,
                              void* d_out, int out_size, void* d_ws, size_t ws_size,
                              hipStream_t stream) {
    const float* adj = (const float*)d_in[0];
    float* out = (float*)d_out;
    float* rowsum = (float*)d_ws;        // N_CELL floats
    float* colsum = rowsum + N_CELL;     // N_DRUG floats

    // zero the atomic accumulators (contiguous 48 KB)
    (void)hipMemsetAsync(d_ws, 0, (N_CELL + N_DRUG) * sizeof(float), stream);

    mega_kernel<<<MEGA_BLOCKS, 256, 0, stream>>>(adj, rowsum, colsum, out + OFF2);
    scale_kernel<<<SCALE_TILES + DIAG_BLOCKS, 256, 0, stream>>>(adj, rowsum, colsum, out);
}